// Round 3
// baseline (398.000 us; speedup 1.0000x reference)
//
#include <hip/hip_runtime.h>

#define NN 10000
#define EE 320000
#define ET (EE + NN)      // 330000 edges incl self-loops
#define FIN 256
#define HD 128
#define NEG 0.2f

#define GB1 625                     // gemm blocks in fused K1 (NN/16)
#define GHIST ((ET + 255) / 256)    // 1290 hist blocks
#define AGG_BLOCKS (NN / 4)         // 2500 blocks, 4 waves each, wave-per-node

// Inputs fp32, edge_index int32, OUTPUT fp32.

// ---------------- K1: gemm1 (blocks 0..624) fused with hist+rank (blocks 625..) --------
// hist's ~330K global atomic-returns hide under the GEMM's compute occupancy.

__global__ __launch_bounds__(256) void k_gemm1_hist(
        const float* __restrict__ x, const float* __restrict__ W,
        const float* __restrict__ atts, const float* __restrict__ attd,
        float* __restrict__ h, float* __restrict__ a_s, float* __restrict__ a_d,
        const int* __restrict__ ei, int* __restrict__ counts, int* __restrict__ rank) {
    __shared__ float xs[16 * FIN];   // 16 KB (reserved but unused by hist blocks)
    int t = threadIdx.x;

    if (blockIdx.x >= GB1) {
        // ---- histogram part: one edge per thread ----
        int i = (blockIdx.x - GB1) * 256 + t;
        if (i < ET) {
            int d = (i < EE) ? ei[EE + i] : (i - EE);
            rank[i] = atomicAdd(&counts[d], 1);
        }
        return;
    }

    // ---- gemm1 part: h = x @ W1, plus a_s/a_d row dots ----
    int m0 = blockIdx.x * 16;
    const float4* xv = (const float4*)(x + (size_t)m0 * FIN);
    float4* xsv = (float4*)xs;
    #pragma unroll
    for (int i = 0; i < 4; i++)      // 16*256/4 = 1024 float4 / 256 threads
        xsv[t + 256 * i] = xv[t + 256 * i];
    __syncthreads();

    int g = t >> 6;
    int tt = t & 63;
    int f = tt * 2;
    const float* xg = xs + g * 4 * FIN;

    float2 acc[4];
    #pragma unroll
    for (int m = 0; m < 4; m++) acc[m] = make_float2(0.f, 0.f);

    for (int k = 0; k < FIN; k += 4) {
        float2 w0 = *(const float2*)&W[(k + 0) * HD + f];
        float2 w1 = *(const float2*)&W[(k + 1) * HD + f];
        float2 w2 = *(const float2*)&W[(k + 2) * HD + f];
        float2 w3 = *(const float2*)&W[(k + 3) * HD + f];
        #pragma unroll
        for (int m = 0; m < 4; m++) {
            float4 xk = *(const float4*)&xg[m * FIN + k];
            acc[m].x += xk.x * w0.x; acc[m].y += xk.x * w0.y;
            acc[m].x += xk.y * w1.x; acc[m].y += xk.y * w1.y;
            acc[m].x += xk.z * w2.x; acc[m].y += xk.z * w2.y;
            acc[m].x += xk.w * w3.x; acc[m].y += xk.w * w3.y;
        }
    }

    float2 ats = *(const float2*)&atts[f];
    float2 atd = *(const float2*)&attd[f];
    #pragma unroll
    for (int m = 0; m < 4; m++) {
        int node = m0 + g * 4 + m;
        *(float2*)&h[(size_t)node * HD + f] = acc[m];
        float vs = acc[m].x * ats.x + acc[m].y * ats.y;
        float vd = acc[m].x * atd.x + acc[m].y * atd.y;
        #pragma unroll
        for (int off = 32; off > 0; off >>= 1) {
            vs += __shfl_down(vs, off);
            vd += __shfl_down(vd, off);
        }
        if (tt == 0) { a_s[node] = vs; a_d[node] = vd; }
    }
}

// ---------------- scan: single 1024-thread block, counts -> offsets[NN+1] ----------------

__global__ __launch_bounds__(1024) void k_scan(const int* __restrict__ counts,
                                               int* __restrict__ offsets) {
    const int CHUNK = 10;   // 1024*10 = 10240 >= 10000
    __shared__ int wsum[16];
    int t = threadIdx.x;
    int lane = t & 63;
    int wid = t >> 6;
    int base = t * CHUNK;
    int c[CHUNK];
    int s = 0;
    #pragma unroll
    for (int i = 0; i < CHUNK; i++) {
        int idx = base + i;
        c[i] = (idx < NN) ? counts[idx] : 0;
        s += c[i];
    }
    int ps = s;
    #pragma unroll
    for (int off = 1; off < 64; off <<= 1) {
        int v = __shfl_up(ps, off);
        if (lane >= off) ps += v;
    }
    if (lane == 63) wsum[wid] = ps;
    __syncthreads();
    if (t < 16) {
        int v = wsum[t];
        #pragma unroll
        for (int off = 1; off < 16; off <<= 1) {
            int u = __shfl_up(v, off);
            if (t >= off) v += u;
        }
        wsum[t] = v;
    }
    __syncthreads();
    int wbase = (wid > 0) ? wsum[wid - 1] : 0;
    int run = wbase + ps - s;
    #pragma unroll
    for (int i = 0; i < CHUNK; i++) {
        int idx = base + i;
        if (idx < NN) { offsets[idx] = run; run += c[i]; }
    }
    if (t == 1023) offsets[NN] = wbase + ps;
}

// ---------------- scatter: atomic-free, position = offsets[dst] + rank ----------------

__global__ __launch_bounds__(256) void k_scatter(const int* __restrict__ ei,
                                                 const int* __restrict__ rank,
                                                 const int* __restrict__ offsets,
                                                 int* __restrict__ srclist) {
    int i = blockIdx.x * blockDim.x + threadIdx.x;
    if (i >= ET) return;
    int s, d;
    if (i < EE) { s = ei[i]; d = ei[EE + i]; }
    else        { s = i - EE; d = s; }
    srclist[offsets[d] + rank[i]] = s;
}

// ---------------- aggregation: ONE WAVE per dst node, no LDS, no syncthreads ----------
// Lane owns float2 of the 128-float row; 64 lanes x 8 B = 512 B coalesced per edge.
// z is identical across lanes (broadcast inputs) -> no reduction needed at all.

__device__ __forceinline__ float edge_w(float as_v, float adn) {
    float e = as_v + adn;
    e = (e > 0.f) ? e : NEG * e;
    return __expf(e);
}

__global__ __launch_bounds__(256) void k_agg1(const int* __restrict__ offsets,
                       const int* __restrict__ srclist,
                       const float* __restrict__ a_s,
                       const float* __restrict__ a_d,
                       const float2* __restrict__ h2,
                       const float* __restrict__ bias,
                       float* __restrict__ g) {
    int t = threadIdx.x;
    int node = blockIdx.x * 4 + (t >> 6);
    int lane = t & 63;
    int p = offsets[node], end = offsets[node + 1];
    float adn = a_d[node];
    float ax = 0.f, ay = 0.f, z = 0.f;
    for (; p + 3 < end; p += 4) {
        int s0 = srclist[p], s1 = srclist[p + 1], s2 = srclist[p + 2], s3 = srclist[p + 3];
        float2 v0 = h2[(size_t)s0 * 64 + lane];
        float2 v1 = h2[(size_t)s1 * 64 + lane];
        float2 v2 = h2[(size_t)s2 * 64 + lane];
        float2 v3 = h2[(size_t)s3 * 64 + lane];
        float w0 = edge_w(a_s[s0], adn);
        float w1 = edge_w(a_s[s1], adn);
        float w2 = edge_w(a_s[s2], adn);
        float w3 = edge_w(a_s[s3], adn);
        z += (w0 + w1) + (w2 + w3);
        ax += w0 * v0.x + w1 * v1.x + w2 * v2.x + w3 * v3.x;
        ay += w0 * v0.y + w1 * v1.y + w2 * v2.y + w3 * v3.y;
    }
    for (; p < end; p++) {
        int s0 = srclist[p];
        float2 v0 = h2[(size_t)s0 * 64 + lane];
        float w0 = edge_w(a_s[s0], adn);
        z += w0;
        ax += w0 * v0.x;
        ay += w0 * v0.y;
    }
    float2 b = ((const float2*)bias)[lane];
    float ox = ax / z + b.x;
    float oy = ay / z + b.y;
    ox = (ox > 0.f) ? ox : 0.f;
    oy = (oy > 0.f) ? oy : 0.f;
    ((float2*)g)[(size_t)node * 64 + lane] = make_float2(ox, oy);
}

// ---------------- GEMM layer 2: h = g1 @ W2 (K=128) ----------------

__global__ __launch_bounds__(256) void k_gemm2(const float* __restrict__ x,
                        const float* __restrict__ W,
                        const float* __restrict__ atts,
                        const float* __restrict__ attd,
                        float* __restrict__ h,
                        float* __restrict__ a_s,
                        float* __restrict__ a_d) {
    __shared__ float xs[16 * HD];    // 8 KB
    int t = threadIdx.x;
    int m0 = blockIdx.x * 16;
    const float4* xv = (const float4*)(x + (size_t)m0 * HD);
    float4* xsv = (float4*)xs;
    #pragma unroll
    for (int i = 0; i < 2; i++)
        xsv[t + 256 * i] = xv[t + 256 * i];
    __syncthreads();

    int g = t >> 6;
    int tt = t & 63;
    int f = tt * 2;
    const float* xg = xs + g * 4 * HD;

    float2 acc[4];
    #pragma unroll
    for (int m = 0; m < 4; m++) acc[m] = make_float2(0.f, 0.f);

    for (int k = 0; k < HD; k += 4) {
        float2 w0 = *(const float2*)&W[(k + 0) * HD + f];
        float2 w1 = *(const float2*)&W[(k + 1) * HD + f];
        float2 w2 = *(const float2*)&W[(k + 2) * HD + f];
        float2 w3 = *(const float2*)&W[(k + 3) * HD + f];
        #pragma unroll
        for (int m = 0; m < 4; m++) {
            float4 xk = *(const float4*)&xg[m * HD + k];
            acc[m].x += xk.x * w0.x; acc[m].y += xk.x * w0.y;
            acc[m].x += xk.y * w1.x; acc[m].y += xk.y * w1.y;
            acc[m].x += xk.z * w2.x; acc[m].y += xk.z * w2.y;
            acc[m].x += xk.w * w3.x; acc[m].y += xk.w * w3.y;
        }
    }

    float2 ats = *(const float2*)&atts[f];
    float2 atd = *(const float2*)&attd[f];
    #pragma unroll
    for (int m = 0; m < 4; m++) {
        int node = m0 + g * 4 + m;
        *(float2*)&h[(size_t)node * HD + f] = acc[m];
        float vs = acc[m].x * ats.x + acc[m].y * ats.y;
        float vd = acc[m].x * atd.x + acc[m].y * atd.y;
        #pragma unroll
        for (int off = 32; off > 0; off >>= 1) {
            vs += __shfl_down(vs, off);
            vd += __shfl_down(vd, off);
        }
        if (tt == 0) { a_s[node] = vs; a_d[node] = vd; }
    }
}

// ---------------- agg2 + reduce_dim + last-block classifier ----------------
// Wave-per-node; r[n] = relu(agg+b2).Wr + br. The LAST block (done-counter) then
// deterministically computes out = r @ Wc + bc — saves a dispatch and a 255-CU-idle hole.

__global__ __launch_bounds__(256) void k_agg2_cls(const int* __restrict__ offsets,
                       const int* __restrict__ srclist,
                       const float* __restrict__ a_s,
                       const float* __restrict__ a_d,
                       const float2* __restrict__ h2,
                       const float* __restrict__ bias,
                       const float* __restrict__ Wr,
                       const float* __restrict__ br,
                       float* __restrict__ r,
                       const float* __restrict__ Wc,
                       const float* __restrict__ bc,
                       float* __restrict__ out,
                       int* __restrict__ done) {
    __shared__ int isLast;
    __shared__ float s0[4], s1[4];
    int t = threadIdx.x;
    int node = blockIdx.x * 4 + (t >> 6);
    int lane = t & 63;
    int p = offsets[node], end = offsets[node + 1];
    float adn = a_d[node];
    float ax = 0.f, ay = 0.f, z = 0.f;
    for (; p + 3 < end; p += 4) {
        int e0 = srclist[p], e1 = srclist[p + 1], e2 = srclist[p + 2], e3 = srclist[p + 3];
        float2 v0 = h2[(size_t)e0 * 64 + lane];
        float2 v1 = h2[(size_t)e1 * 64 + lane];
        float2 v2 = h2[(size_t)e2 * 64 + lane];
        float2 v3 = h2[(size_t)e3 * 64 + lane];
        float w0 = edge_w(a_s[e0], adn);
        float w1 = edge_w(a_s[e1], adn);
        float w2 = edge_w(a_s[e2], adn);
        float w3 = edge_w(a_s[e3], adn);
        z += (w0 + w1) + (w2 + w3);
        ax += w0 * v0.x + w1 * v1.x + w2 * v2.x + w3 * v3.x;
        ay += w0 * v0.y + w1 * v1.y + w2 * v2.y + w3 * v3.y;
    }
    for (; p < end; p++) {
        int e0 = srclist[p];
        float2 v0 = h2[(size_t)e0 * 64 + lane];
        float w0 = edge_w(a_s[e0], adn);
        z += w0;
        ax += w0 * v0.x;
        ay += w0 * v0.y;
    }
    float2 b = ((const float2*)bias)[lane];
    float ox = ax / z + b.x;
    float oy = ay / z + b.y;
    ox = (ox > 0.f) ? ox : 0.f;
    oy = (oy > 0.f) ? oy : 0.f;
    float2 wr = ((const float2*)Wr)[lane];
    float part = ox * wr.x + oy * wr.y;
    #pragma unroll
    for (int off = 32; off > 0; off >>= 1) part += __shfl_down(part, off);
    if (lane == 0) r[node] = part + br[0];

    // ---- last-block classifier ----
    __threadfence();                 // publish this block's r writes device-wide
    __syncthreads();                 // all 4 waves' fences complete
    if (t == 0) isLast = (atomicAdd(done, 1) == gridDim.x - 1);
    __syncthreads();
    if (!isLast) return;
    __threadfence();                 // acquire: observe all published r
    float c0 = 0.f, c1 = 0.f;
    for (int n = t; n < NN; n += 256) {
        float rv = r[n];
        c0 += rv * Wc[2 * n];
        c1 += rv * Wc[2 * n + 1];
    }
    #pragma unroll
    for (int off = 32; off > 0; off >>= 1) {
        c0 += __shfl_down(c0, off);
        c1 += __shfl_down(c1, off);
    }
    if (lane == 0) { s0[t >> 6] = c0; s1[t >> 6] = c1; }
    __syncthreads();
    if (t == 0) {
        out[0] = s0[0] + s0[1] + s0[2] + s0[3] + bc[0];
        out[1] = s1[0] + s1[1] + s1[2] + s1[3] + bc[1];
    }
}

// ---------------- launch ----------------

extern "C" void kernel_launch(void* const* d_in, const int* in_sizes, int n_in,
                              void* d_out, int out_size, void* d_ws, size_t ws_size,
                              hipStream_t stream) {
    const float* x    = (const float*)d_in[0];
    const int*   ei   = (const int*)d_in[1];
    const float* W1   = (const float*)d_in[2];
    const float* as1  = (const float*)d_in[3];
    const float* ad1  = (const float*)d_in[4];
    const float* b1   = (const float*)d_in[5];
    const float* W2   = (const float*)d_in[6];
    const float* as2  = (const float*)d_in[7];
    const float* ad2  = (const float*)d_in[8];
    const float* b2   = (const float*)d_in[9];
    const float* Wr   = (const float*)d_in[10];
    const float* br   = (const float*)d_in[11];
    const float* Wc   = (const float*)d_in[12];
    const float* bc   = (const float*)d_in[13];
    float* out = (float*)d_out;

    // workspace layout
    float* h     = (float*)d_ws;                 // NN*HD (16B aligned)
    float* g1    = h + (size_t)NN * HD;          // NN*HD
    float* a_s   = g1 + (size_t)NN * HD;         // NN
    float* a_d   = a_s + NN;                     // NN
    float* r     = a_d + NN;                     // NN
    int* counts  = (int*)(r + NN);               // NN
    int* done    = counts + NN;                  // 1
    int* offsets = done + 1;                     // NN+1
    int* rank    = offsets + NN + 1;             // ET
    int* srclist = rank + ET;                    // ET

    // zero counts + done in one memset (captured as a single fill node)
    hipMemsetAsync(counts, 0, (NN + 1) * sizeof(int), stream);

    // K1: gemm1 || hist(rank)
    k_gemm1_hist<<<GB1 + GHIST, 256, 0, stream>>>(x, W1, as1, ad1, h, a_s, a_d,
                                                  ei, counts, rank);
    // scan + scatter
    k_scan<<<1, 1024, 0, stream>>>(counts, offsets);
    k_scatter<<<GHIST, 256, 0, stream>>>(ei, rank, offsets, srclist);

    // layer 1 aggregation
    k_agg1<<<AGG_BLOCKS, 256, 0, stream>>>(offsets, srclist, a_s, a_d,
                                           (const float2*)h, b1, g1);
    // layer 2
    k_gemm2<<<GB1, 256, 0, stream>>>(g1, W2, as2, ad2, h, a_s, a_d);
    k_agg2_cls<<<AGG_BLOCKS, 256, 0, stream>>>(offsets, srclist, a_s, a_d,
                                               (const float2*)h, b2, Wr, br, r,
                                               Wc, bc, out, done);
}

// Round 4
// 189.241 us; speedup vs baseline: 2.1031x; 2.1031x over previous
//
#include <hip/hip_runtime.h>

#define NN 10000
#define EE 320000
#define ET (EE + NN)      // 330000 edges incl self-loops
#define FIN 256
#define HD 128
#define NEG 0.2f

#define GB1 625                     // gemm1 blocks in fused K1 (NN/16)
#define GHIST ((ET + 255) / 256)    // 1290 hist blocks

// Inputs fp32, edge_index int32, OUTPUT fp32.

// ---------------- K1: gemm1 (blocks 0..624) fused with hist+rank (blocks 625..) --------
// hist's ~330K global atomic-returns hide under the GEMM's compute occupancy.

__global__ __launch_bounds__(256) void k_gemm1_hist(
        const float* __restrict__ x, const float* __restrict__ W,
        const float* __restrict__ atts, const float* __restrict__ attd,
        float* __restrict__ h, float* __restrict__ a_s, float* __restrict__ a_d,
        const int* __restrict__ ei, int* __restrict__ counts, int* __restrict__ rank) {
    __shared__ float xs[16 * FIN];   // 16 KB (unused by hist blocks)
    int t = threadIdx.x;

    if (blockIdx.x >= GB1) {
        // ---- histogram part: one edge per thread ----
        int i = (blockIdx.x - GB1) * 256 + t;
        if (i < ET) {
            int d = (i < EE) ? ei[EE + i] : (i - EE);
            rank[i] = atomicAdd(&counts[d], 1);
        }
        return;
    }

    // ---- gemm1 part: h = x @ W1, plus a_s/a_d row dots ----
    int m0 = blockIdx.x * 16;
    const float4* xv = (const float4*)(x + (size_t)m0 * FIN);
    float4* xsv = (float4*)xs;
    #pragma unroll
    for (int i = 0; i < 4; i++)      // 16*256/4 = 1024 float4 / 256 threads
        xsv[t + 256 * i] = xv[t + 256 * i];
    __syncthreads();

    int g = t >> 6;
    int tt = t & 63;
    int f = tt * 2;
    const float* xg = xs + g * 4 * FIN;

    float2 acc[4];
    #pragma unroll
    for (int m = 0; m < 4; m++) acc[m] = make_float2(0.f, 0.f);

    for (int k = 0; k < FIN; k += 4) {
        float2 w0 = *(const float2*)&W[(k + 0) * HD + f];
        float2 w1 = *(const float2*)&W[(k + 1) * HD + f];
        float2 w2 = *(const float2*)&W[(k + 2) * HD + f];
        float2 w3 = *(const float2*)&W[(k + 3) * HD + f];
        #pragma unroll
        for (int m = 0; m < 4; m++) {
            float4 xk = *(const float4*)&xg[m * FIN + k];
            acc[m].x += xk.x * w0.x; acc[m].y += xk.x * w0.y;
            acc[m].x += xk.y * w1.x; acc[m].y += xk.y * w1.y;
            acc[m].x += xk.z * w2.x; acc[m].y += xk.z * w2.y;
            acc[m].x += xk.w * w3.x; acc[m].y += xk.w * w3.y;
        }
    }

    float2 ats = *(const float2*)&atts[f];
    float2 atd = *(const float2*)&attd[f];
    #pragma unroll
    for (int m = 0; m < 4; m++) {
        int node = m0 + g * 4 + m;
        *(float2*)&h[(size_t)node * HD + f] = acc[m];
        float vs = acc[m].x * ats.x + acc[m].y * ats.y;
        float vd = acc[m].x * atd.x + acc[m].y * atd.y;
        #pragma unroll
        for (int off = 32; off > 0; off >>= 1) {
            vs += __shfl_down(vs, off);
            vd += __shfl_down(vd, off);
        }
        if (tt == 0) { a_s[node] = vs; a_d[node] = vd; }
    }
}

// ---------------- scan: single 1024-thread block, counts -> offsets[NN+1] ----------------

__global__ __launch_bounds__(1024) void k_scan(const int* __restrict__ counts,
                                               int* __restrict__ offsets) {
    const int CHUNK = 10;   // 1024*10 = 10240 >= 10000
    __shared__ int wsum[16];
    int t = threadIdx.x;
    int lane = t & 63;
    int wid = t >> 6;
    int base = t * CHUNK;
    int c[CHUNK];
    int s = 0;
    #pragma unroll
    for (int i = 0; i < CHUNK; i++) {
        int idx = base + i;
        c[i] = (idx < NN) ? counts[idx] : 0;
        s += c[i];
    }
    int ps = s;
    #pragma unroll
    for (int off = 1; off < 64; off <<= 1) {
        int v = __shfl_up(ps, off);
        if (lane >= off) ps += v;
    }
    if (lane == 63) wsum[wid] = ps;
    __syncthreads();
    if (t < 16) {
        int v = wsum[t];
        #pragma unroll
        for (int off = 1; off < 16; off <<= 1) {
            int u = __shfl_up(v, off);
            if (t >= off) v += u;
        }
        wsum[t] = v;
    }
    __syncthreads();
    int wbase = (wid > 0) ? wsum[wid - 1] : 0;
    int run = wbase + ps - s;
    #pragma unroll
    for (int i = 0; i < CHUNK; i++) {
        int idx = base + i;
        if (idx < NN) { offsets[idx] = run; run += c[i]; }
    }
    if (t == 1023) offsets[NN] = wbase + ps;
}

// ---------------- scatter: atomic-free, position = offsets[dst] + rank ----------------

__global__ __launch_bounds__(256) void k_scatter(const int* __restrict__ ei,
                                                 const int* __restrict__ rank,
                                                 const int* __restrict__ offsets,
                                                 int* __restrict__ srclist) {
    int i = blockIdx.x * blockDim.x + threadIdx.x;
    if (i >= ET) return;
    int s, d;
    if (i < EE) { s = ei[i]; d = ei[EE + i]; }
    else        { s = i - EE; d = s; }
    srclist[offsets[d] + rank[i]] = s;
}

// ---------------- aggregation: block per dst node, float4 gathers (PROVEN form) -------
// 4 edge-slots x 32 lanes; lane q owns float4 q of the 128-float h row.
// exp fused (max-subtraction skipped: shift-invariant, e is O(1)).
// z > 0 structurally (self-loop per node).

__device__ __forceinline__ float edge_w(float as_v, float adn) {
    float e = as_v + adn;
    e = (e > 0.f) ? e : NEG * e;
    return __expf(e);
}

__global__ void k_agg1(const int* __restrict__ offsets,
                       const int* __restrict__ srclist,
                       const float* __restrict__ a_s,
                       const float* __restrict__ a_d,
                       const float4* __restrict__ h4,
                       const float* __restrict__ bias,
                       float* __restrict__ g) {
    __shared__ float accs[4][HD];
    __shared__ float zs[4];
    int node = blockIdx.x;
    int t = threadIdx.x;
    int slot = t >> 5, q = t & 31;
    int beg = offsets[node], end = offsets[node + 1];
    float adn = a_d[node];
    float4 acc = make_float4(0.f, 0.f, 0.f, 0.f);
    float z = 0.f;
    int p = beg + slot;
    for (; p + 4 < end; p += 8) {
        int s0 = srclist[p];
        int s1 = srclist[p + 4];
        float4 h0 = h4[(size_t)s0 * 32 + q];
        float4 h1 = h4[(size_t)s1 * 32 + q];
        float w0 = edge_w(a_s[s0], adn);
        float w1 = edge_w(a_s[s1], adn);
        z += w0 + w1;
        acc.x += w0 * h0.x + w1 * h1.x;
        acc.y += w0 * h0.y + w1 * h1.y;
        acc.z += w0 * h0.z + w1 * h1.z;
        acc.w += w0 * h0.w + w1 * h1.w;
    }
    if (p < end) {
        int s0 = srclist[p];
        float4 h0 = h4[(size_t)s0 * 32 + q];
        float w0 = edge_w(a_s[s0], adn);
        z += w0;
        acc.x += w0 * h0.x; acc.y += w0 * h0.y;
        acc.z += w0 * h0.z; acc.w += w0 * h0.w;
    }
    *(float4*)&accs[slot][q * 4] = acc;
    if (q == 0) zs[slot] = z;
    __syncthreads();
    float v = accs[0][t] + accs[1][t] + accs[2][t] + accs[3][t];
    float zz = zs[0] + zs[1] + zs[2] + zs[3];
    float o = v / zz + bias[t];
    g[(size_t)node * HD + t] = (o > 0.f) ? o : 0.f;   // relu
}

// ---------------- GEMM layer 2: h = g1 @ W2 (K=128) ----------------

__global__ __launch_bounds__(256) void k_gemm2(const float* __restrict__ x,
                        const float* __restrict__ W,
                        const float* __restrict__ atts,
                        const float* __restrict__ attd,
                        float* __restrict__ h,
                        float* __restrict__ a_s,
                        float* __restrict__ a_d) {
    __shared__ float xs[16 * HD];    // 8 KB
    int t = threadIdx.x;
    int m0 = blockIdx.x * 16;
    const float4* xv = (const float4*)(x + (size_t)m0 * HD);
    float4* xsv = (float4*)xs;
    #pragma unroll
    for (int i = 0; i < 2; i++)
        xsv[t + 256 * i] = xv[t + 256 * i];
    __syncthreads();

    int g = t >> 6;
    int tt = t & 63;
    int f = tt * 2;
    const float* xg = xs + g * 4 * HD;

    float2 acc[4];
    #pragma unroll
    for (int m = 0; m < 4; m++) acc[m] = make_float2(0.f, 0.f);

    for (int k = 0; k < HD; k += 4) {
        float2 w0 = *(const float2*)&W[(k + 0) * HD + f];
        float2 w1 = *(const float2*)&W[(k + 1) * HD + f];
        float2 w2 = *(const float2*)&W[(k + 2) * HD + f];
        float2 w3 = *(const float2*)&W[(k + 3) * HD + f];
        #pragma unroll
        for (int m = 0; m < 4; m++) {
            float4 xk = *(const float4*)&xg[m * HD + k];
            acc[m].x += xk.x * w0.x; acc[m].y += xk.x * w0.y;
            acc[m].x += xk.y * w1.x; acc[m].y += xk.y * w1.y;
            acc[m].x += xk.z * w2.x; acc[m].y += xk.z * w2.y;
            acc[m].x += xk.w * w3.x; acc[m].y += xk.w * w3.y;
        }
    }

    float2 ats = *(const float2*)&atts[f];
    float2 atd = *(const float2*)&attd[f];
    #pragma unroll
    for (int m = 0; m < 4; m++) {
        int node = m0 + g * 4 + m;
        *(float2*)&h[(size_t)node * HD + f] = acc[m];
        float vs = acc[m].x * ats.x + acc[m].y * ats.y;
        float vd = acc[m].x * atd.x + acc[m].y * atd.y;
        #pragma unroll
        for (int off = 32; off > 0; off >>= 1) {
            vs += __shfl_down(vs, off);
            vd += __shfl_down(vd, off);
        }
        if (tt == 0) { a_s[node] = vs; a_d[node] = vd; }
    }
}

// ---------------- agg2 + reduce_dim fused: r[n] = relu(agg+b2) . Wr + br (PROVEN) -----

__global__ void k_agg2(const int* __restrict__ offsets,
                       const int* __restrict__ srclist,
                       const float* __restrict__ a_s,
                       const float* __restrict__ a_d,
                       const float4* __restrict__ h4,
                       const float* __restrict__ bias,
                       const float* __restrict__ Wr,
                       const float* __restrict__ br,
                       float* __restrict__ r) {
    __shared__ float accs[4][HD];
    __shared__ float zs[4];
    __shared__ float red[2];
    int node = blockIdx.x;
    int t = threadIdx.x;
    int slot = t >> 5, q = t & 31;
    int beg = offsets[node], end = offsets[node + 1];
    float adn = a_d[node];
    float4 acc = make_float4(0.f, 0.f, 0.f, 0.f);
    float z = 0.f;
    int p = beg + slot;
    for (; p + 4 < end; p += 8) {
        int s0 = srclist[p];
        int s1 = srclist[p + 4];
        float4 h0 = h4[(size_t)s0 * 32 + q];
        float4 h1 = h4[(size_t)s1 * 32 + q];
        float w0 = edge_w(a_s[s0], adn);
        float w1 = edge_w(a_s[s1], adn);
        z += w0 + w1;
        acc.x += w0 * h0.x + w1 * h1.x;
        acc.y += w0 * h0.y + w1 * h1.y;
        acc.z += w0 * h0.z + w1 * h1.z;
        acc.w += w0 * h0.w + w1 * h1.w;
    }
    if (p < end) {
        int s0 = srclist[p];
        float4 h0 = h4[(size_t)s0 * 32 + q];
        float w0 = edge_w(a_s[s0], adn);
        z += w0;
        acc.x += w0 * h0.x; acc.y += w0 * h0.y;
        acc.z += w0 * h0.z; acc.w += w0 * h0.w;
    }
    *(float4*)&accs[slot][q * 4] = acc;
    if (q == 0) zs[slot] = z;
    __syncthreads();
    float v = accs[0][t] + accs[1][t] + accs[2][t] + accs[3][t];
    float zz = zs[0] + zs[1] + zs[2] + zs[3];
    float o = v / zz + bias[t];
    o = (o > 0.f) ? o : 0.f;
    float part = o * Wr[t];
    #pragma unroll
    for (int off = 32; off > 0; off >>= 1) part += __shfl_down(part, off);
    if ((t & 63) == 0) red[t >> 6] = part;
    __syncthreads();
    if (t == 0) r[node] = red[0] + red[1] + br[0];
}

// ---------------- classifier: out[c] = sum_n r[n]*Wc[n,c] + bc[c] ----------------

__global__ __launch_bounds__(1024) void k_cls(const float* __restrict__ r,
                      const float* __restrict__ Wc,
                      const float* __restrict__ bc,
                      float* __restrict__ out) {
    __shared__ float red0[16], red1[16];
    int t = threadIdx.x;
    float c0 = 0.f, c1 = 0.f;
    for (int n = t; n < NN; n += 1024) {
        float rv = r[n];
        c0 += rv * Wc[2 * n];
        c1 += rv * Wc[2 * n + 1];
    }
    #pragma unroll
    for (int off = 32; off > 0; off >>= 1) {
        c0 += __shfl_down(c0, off);
        c1 += __shfl_down(c1, off);
    }
    if ((t & 63) == 0) { red0[t >> 6] = c0; red1[t >> 6] = c1; }
    __syncthreads();
    if (t == 0) {
        float s0 = bc[0], s1 = bc[1];
        #pragma unroll
        for (int i = 0; i < 16; i++) { s0 += red0[i]; s1 += red1[i]; }
        out[0] = s0;
        out[1] = s1;
    }
}

// ---------------- launch ----------------

extern "C" void kernel_launch(void* const* d_in, const int* in_sizes, int n_in,
                              void* d_out, int out_size, void* d_ws, size_t ws_size,
                              hipStream_t stream) {
    const float* x    = (const float*)d_in[0];
    const int*   ei   = (const int*)d_in[1];
    const float* W1   = (const float*)d_in[2];
    const float* as1  = (const float*)d_in[3];
    const float* ad1  = (const float*)d_in[4];
    const float* b1   = (const float*)d_in[5];
    const float* W2   = (const float*)d_in[6];
    const float* as2  = (const float*)d_in[7];
    const float* ad2  = (const float*)d_in[8];
    const float* b2   = (const float*)d_in[9];
    const float* Wr   = (const float*)d_in[10];
    const float* br   = (const float*)d_in[11];
    const float* Wc   = (const float*)d_in[12];
    const float* bc   = (const float*)d_in[13];
    float* out = (float*)d_out;

    // workspace layout
    float* h     = (float*)d_ws;                 // NN*HD (16B aligned)
    float* g1    = h + (size_t)NN * HD;          // NN*HD
    float* a_s   = g1 + (size_t)NN * HD;         // NN
    float* a_d   = a_s + NN;                     // NN
    float* r     = a_d + NN;                     // NN
    int* counts  = (int*)(r + NN);               // NN
    int* offsets = counts + NN;                  // NN+1
    int* rank    = offsets + NN + 1;             // ET
    int* srclist = rank + ET;                    // ET

    // zero counts (single fill node)
    hipMemsetAsync(counts, 0, NN * sizeof(int), stream);

    // K1: gemm1 || hist(rank)
    k_gemm1_hist<<<GB1 + GHIST, 256, 0, stream>>>(x, W1, as1, ad1, h, a_s, a_d,
                                                  ei, counts, rank);
    // scan + scatter
    k_scan<<<1, 1024, 0, stream>>>(counts, offsets);
    k_scatter<<<GHIST, 256, 0, stream>>>(ei, rank, offsets, srclist);

    // layer 1 aggregation
    k_agg1<<<NN, 128, 0, stream>>>(offsets, srclist, a_s, a_d,
                                   (const float4*)h, b1, g1);
    // layer 2
    k_gemm2<<<GB1, 256, 0, stream>>>(g1, W2, as2, ad2, h, a_s, a_d);
    k_agg2<<<NN, 128, 0, stream>>>(offsets, srclist, a_s, a_d,
                                   (const float4*)h, b2, Wr, br, r);
    // classifier
    k_cls<<<1, 1024, 0, stream>>>(r, Wc, bc, out);
}